// Round 8
// baseline (869.404 us; speedup 1.0000x reference)
//
#include <hip/hip_runtime.h>

// Problem constants
constexpr int Bsz = 2, Tsz = 512, Csz = 1024, Hsz = 16, Dsz = 64, CSz = 64;
constexpr int NCHUNK = 8, OW = 8;

typedef __attribute__((ext_vector_type(8))) _Float16 half8;
typedef __attribute__((ext_vector_type(4))) _Float16 half4;
typedef __attribute__((ext_vector_type(2))) _Float16 half2v;
typedef __attribute__((ext_vector_type(2))) __fp16 fp16x2;
typedef __attribute__((ext_vector_type(16))) float f32x16;

constexpr float INV_S = 1.0f / 2048.0f;

union H4u { half4 v; half2v p[2]; };

// fp32 v ~= hi + lo/2048 (f16 pair). Proven precision-adequate by pe kernel.
__device__ __forceinline__ void split_f16(float v, _Float16& hi, _Float16& lo) {
  _Float16 h = (_Float16)v;
  float r = v - (float)h;
  hi = h;
  lo = (_Float16)(r * 2048.0f);
}

// Packed 2-value split via v_cvt_pkrtz_f16_f32. RTZ on hi is pair-safe:
// residual is captured exactly in lo.
__device__ __forceinline__ void split2(float a, float b, half2v& h, half2v& l) {
  fp16x2 hh = __builtin_amdgcn_cvt_pkrtz(a, b);
  half2v hv = __builtin_bit_cast(half2v, hh);
  float ra = (a - (float)hv[0]) * 2048.0f;
  float rb = (b - (float)hv[1]) * 2048.0f;
  h = hv;
  l = __builtin_bit_cast(half2v, __builtin_amdgcn_cvt_pkrtz(ra, rb));
}

// 3-MFMA split product with accL chain split in two.
#define MFMA3(accH, accL1, accL2, ah, al, bh, bl)                             \
  accH = __builtin_amdgcn_mfma_f32_32x32x16_f16(ah, bh, accH, 0, 0, 0);       \
  accL1 = __builtin_amdgcn_mfma_f32_32x32x16_f16(ah, bl, accL1, 0, 0, 0);     \
  accL2 = __builtin_amdgcn_mfma_f32_32x32x16_f16(al, bh, accL2, 0, 0, 0);

// XCD-affinity decode: launched bid -> (bh, idx) with XCD(bid)=bid%8 == bh%8.
__device__ __forceinline__ void xcd_decode(int bid, int& bh, int& idx) {
  bh = (((bid >> 3) & 3) << 3) + (bid & 7);
  idx = bid >> 5;
}

// ---------------------------------------------------------------------------
// One-time fp32 -> (hi,lo) f16 plane conversion.
// ---------------------------------------------------------------------------
__global__ __launch_bounds__(256) void split_all_kernel(
    const float* __restrict__ x, const float* __restrict__ Wq,
    const float* __restrict__ Wk, const float* __restrict__ Wv,
    const float* __restrict__ Wo, const float* __restrict__ Wa,
    const float* __restrict__ We, const float* __restrict__ Wt,
    const float* __restrict__ Wg,
    _Float16* __restrict__ xh, _Float16* __restrict__ xl,
    _Float16* __restrict__ Wqh, _Float16* __restrict__ Wql,
    _Float16* __restrict__ Wkh, _Float16* __restrict__ Wkl,
    _Float16* __restrict__ Wvh, _Float16* __restrict__ Wvl,
    _Float16* __restrict__ Woh, _Float16* __restrict__ Wol,
    _Float16* __restrict__ gWh, _Float16* __restrict__ gWl) {
  const int y = blockIdx.y;
  const int tid = threadIdx.x;
  if (y < 5) {
    const float* src = (y == 0 ? x : y == 1 ? Wq : y == 2 ? Wk : y == 3 ? Wv : Wo);
    _Float16* dh = (y == 0 ? xh : y == 1 ? Wqh : y == 2 ? Wkh : y == 3 ? Wvh : Woh);
    _Float16* dl = (y == 0 ? xl : y == 1 ? Wql : y == 2 ? Wkl : y == 3 ? Wvl : Wol);
    size_t i = ((size_t)blockIdx.x * 256 + tid) * 4;
    float4 v = *(const float4*)(src + i);
    H4u h, l;
    split2(v.x, v.y, h.p[0], l.p[0]);
    split2(v.z, v.w, h.p[1], l.p[1]);
    *(half4*)(dh + i) = h.v;
    *(half4*)(dl + i) = l.v;
  } else {
    if (blockIdx.x >= 64) return;
    size_t i = ((size_t)blockIdx.x * 256 + tid) * 4;
    int gsel = (int)(i >> 14);
    int off = (int)(i & 16383);
    const float* src = (gsel == 0 ? Wa : gsel == 1 ? We : gsel == 2 ? Wt : Wg);
    float4 v = *(const float4*)(src + off);
    H4u h, l;
    split2(v.x, v.y, h.p[0], l.p[0]);
    split2(v.z, v.w, h.p[1], l.p[1]);
    *(half4*)(gWh + i) = h.v;
    *(half4*)(gWl + i) = l.v;
  }
}

// ---------------------------------------------------------------------------
// Split-f16 MFMA GEMM core: 64x64 output tile, K=1024, O = A @ B^T.
// ---------------------------------------------------------------------------
__device__ __forceinline__ void gemm64_core(const _Float16* __restrict__ Agh,
                                            const _Float16* __restrict__ Agl,
                                            const _Float16* __restrict__ Bgh,
                                            const _Float16* __restrict__ Bgl,
                                            int m0, int n0, int tid, char* LB,
                                            f32x16& accH, f32x16& accL1, f32x16& accL2) {
  const int lane = tid & 63, wv = tid >> 6;
  const int mb = (wv >> 1) << 5, nb = (wv & 1) << 5;
  const int lr = tid >> 2;             // staging row 0..63
  const int lch = (tid & 3) << 4;      // half col {0,16,32,48}
  const int cb = lch << 1;             // byte col
  const int wb0 = (lr << 7) + (cb ^ ((lr & 7) << 4));
  const int wb1 = (lr << 7) + ((cb + 16) ^ ((lr & 7) << 4));
  const _Float16* pah = Agh + (size_t)(m0 + lr) * Csz + lch;
  const _Float16* pal = Agl + (size_t)(m0 + lr) * Csz + lch;
  const _Float16* pbh = Bgh + (size_t)(n0 + lr) * Csz + lch;
  const _Float16* pbl = Bgl + (size_t)(n0 + lr) * Csz + lch;
  int ra_m[4], ra_n[4];
#pragma unroll
  for (int ks = 0; ks < 4; ++ks) {
    int rm = mb + (lane & 31), rn = nb + (lane & 31);
    int cB = (ks << 5) + ((lane >> 5) << 4);
    ra_m[ks] = (rm << 7) + (cB ^ ((rm & 7) << 4));
    ra_n[ks] = (rn << 7) + (cB ^ ((rn & 7) << 4));
  }
#pragma unroll
  for (int r = 0; r < 16; ++r) { accH[r] = 0.f; accL1[r] = 0.f; accL2[r] = 0.f; }
  for (int k0 = 0; k0 < Csz; k0 += 64) {
    half8 vah0 = *(const half8*)(pah + k0), vah1 = *(const half8*)(pah + k0 + 8);
    half8 val0 = *(const half8*)(pal + k0), val1 = *(const half8*)(pal + k0 + 8);
    half8 vbh0 = *(const half8*)(pbh + k0), vbh1 = *(const half8*)(pbh + k0 + 8);
    half8 vbl0 = *(const half8*)(pbl + k0), vbl1 = *(const half8*)(pbl + k0 + 8);
    __syncthreads();
    *(half8*)(LB + wb0) = vah0;          *(half8*)(LB + wb1) = vah1;
    *(half8*)(LB + 8192 + wb0) = val0;   *(half8*)(LB + 8192 + wb1) = val1;
    *(half8*)(LB + 16384 + wb0) = vbh0;  *(half8*)(LB + 16384 + wb1) = vbh1;
    *(half8*)(LB + 24576 + wb0) = vbl0;  *(half8*)(LB + 24576 + wb1) = vbl1;
    __syncthreads();
    __builtin_amdgcn_s_setprio(1);
#pragma unroll
    for (int ks = 0; ks < 4; ++ks) {
      half8 ah = *(const half8*)(LB + ra_m[ks]);
      half8 al = *(const half8*)(LB + 8192 + ra_m[ks]);
      half8 bh = *(const half8*)(LB + 16384 + ra_n[ks]);
      half8 bl = *(const half8*)(LB + 24576 + ra_n[ks]);
      MFMA3(accH, accL1, accL2, ah, al, bh, bl);
    }
    __builtin_amdgcn_s_setprio(0);
  }
}

// ---------------------------------------------------------------------------
// Fused QKV + gates GEMM via split-f16 MFMA. Grid (16, 49).
// ---------------------------------------------------------------------------
__global__ __launch_bounds__(256) void qkvg_mfma(
    const _Float16* __restrict__ xh, const _Float16* __restrict__ xl,
    const _Float16* __restrict__ Wqh, const _Float16* __restrict__ Wql,
    const _Float16* __restrict__ Wkh, const _Float16* __restrict__ Wkl,
    const _Float16* __restrict__ Wvh, const _Float16* __restrict__ Wvl,
    const _Float16* __restrict__ gWh, const _Float16* __restrict__ gWl,
    float* __restrict__ qlin, float* __restrict__ klin, float* __restrict__ vlin,
    float* __restrict__ ga, float* __restrict__ ge,
    float* __restrict__ gt, float* __restrict__ gg) {
  __shared__ __attribute__((aligned(16))) char LB[32768];
  const int tid = threadIdx.x;
  const int by = blockIdx.y;
  const int m0 = blockIdx.x << 6;
  const _Float16 *Bh, *Bl;
  int n0;
  if (by < 48) {
    const int mat = by >> 4;
    n0 = (by & 15) << 6;
    Bh = (mat == 0 ? Wqh : mat == 1 ? Wkh : Wvh);
    Bl = (mat == 0 ? Wql : mat == 1 ? Wkl : Wvl);
  } else {
    n0 = 0;
    Bh = gWh;
    Bl = gWl;
  }
  f32x16 accH, accL1, accL2;
  gemm64_core(xh, xl, Bh, Bl, m0, n0, tid, LB, accH, accL1, accL2);
  const int lane = tid & 63, wv = tid >> 6;
  const int mb = (wv >> 1) << 5, nb = (wv & 1) << 5;
  const int crow = (lane >> 5) << 2, ccol = lane & 31;
  if (by < 48) {
    const int mat = by >> 4;
    float* O = (mat == 0 ? qlin : mat == 1 ? klin : vlin);
#pragma unroll
    for (int r = 0; r < 16; ++r) {
      int row = mb + crow + (r & 3) + ((r >> 2) << 3);
      O[(size_t)(m0 + row) * Csz + n0 + nb + ccol] = accH[r] + (accL1[r] + accL2[r]) * INV_S;
    }
  } else {
    const int col = nb + ccol;
    const int gsel = col >> 4, h = col & 15;
    float* outp = (gsel == 0 ? ga : gsel == 1 ? ge : gsel == 2 ? gt : gg);
#pragma unroll
    for (int r = 0; r < 16; ++r) {
      int row = mb + crow + (r & 3) + ((r >> 2) << 3);
      float v = accH[r] + (accL1[r] + accL2[r]) * INV_S;
      outp[(size_t)(m0 + row) * Hsz + h] = 1.f / (1.f + expf(-v));
    }
  }
}

// ---------------------------------------------------------------------------
// Out-projection GEMM via split-f16 MFMA. Grid (16,16).
// ---------------------------------------------------------------------------
__global__ __launch_bounds__(256) void out_mfma(
    const _Float16* __restrict__ yh, const _Float16* __restrict__ yl,
    const _Float16* __restrict__ Woh, const _Float16* __restrict__ Wol,
    float* __restrict__ out) {
  __shared__ __attribute__((aligned(16))) char LB[32768];
  const int tid = threadIdx.x;
  const int m0 = blockIdx.x << 6, n0 = blockIdx.y << 6;
  f32x16 accH, accL1, accL2;
  gemm64_core(yh, yl, Woh, Wol, m0, n0, tid, LB, accH, accL1, accL2);
  const int lane = tid & 63, wv = tid >> 6;
  const int mb = (wv >> 1) << 5, nb = (wv & 1) << 5;
  const int crow = (lane >> 5) << 2, ccol = lane & 31;
#pragma unroll
  for (int r = 0; r < 16; ++r) {
    int row = mb + crow + (r & 3) + ((r >> 2) << 3);
    out[(size_t)(m0 + row) * Csz + n0 + nb + ccol] = accH[r] + (accL1[r] + accL2[r]) * INV_S;
  }
}

// ---------------------------------------------------------------------------
// Causal depthwise conv (K=4) + optional rms_norm/poly. Grid (B*T, 3).
// ---------------------------------------------------------------------------
__global__ __launch_bounds__(256) void conv3_kernel(const float* __restrict__ qlin,
                                                    const float* __restrict__ klin,
                                                    const float* __restrict__ vlin,
                                                    const float* __restrict__ cqw,
                                                    const float* __restrict__ ckw,
                                                    const float* __restrict__ cvw,
                                                    const float* __restrict__ cqb,
                                                    const float* __restrict__ ckb,
                                                    const float* __restrict__ cvb,
                                                    float* __restrict__ qp,
                                                    float* __restrict__ kp,
                                                    float* __restrict__ vp) {
  const int sel = blockIdx.y;
  const float* lin = (sel == 0 ? qlin : sel == 1 ? klin : vlin);
  const float* w = (sel == 0 ? cqw : sel == 1 ? ckw : cvw);
  const float* bias = (sel == 0 ? cqb : sel == 1 ? ckb : cvb);
  float* out = (sel == 0 ? qp : sel == 1 ? kp : vp);
  const int do_norm = (sel < 2);
  const int bt = blockIdx.x;
  const int b = bt >> 9, t = bt & 511;
  const int tid = threadIdx.x;
  const int c0 = tid << 2;
  float4 bv = *(const float4*)&bias[c0];
  float v0 = bv.x, v1 = bv.y, v2 = bv.z, v3 = bv.w;
  float4 w0 = *(const float4*)&w[(c0 + 0) * 4];
  float4 w1 = *(const float4*)&w[(c0 + 1) * 4];
  float4 w2 = *(const float4*)&w[(c0 + 2) * 4];
  float4 w3 = *(const float4*)&w[(c0 + 3) * 4];
  const float* base = lin + (size_t)b * Tsz * Csz + c0;
#pragma unroll
  for (int j = 0; j < 4; ++j) {
    int tt = t - 3 + j;
    if (tt < 0) continue;
    float4 xv = *(const float4*)(base + (size_t)tt * Csz);
    v0 += xv.x * (&w0.x)[j];
    v1 += xv.y * (&w1.x)[j];
    v2 += xv.z * (&w2.x)[j];
    v3 += xv.w * (&w3.x)[j];
  }
  if (do_norm) {
    float ss = v0 * v0 + v1 * v1 + v2 * v2 + v3 * v3;
    ss += __shfl_xor(ss, 1, 16);
    ss += __shfl_xor(ss, 2, 16);
    ss += __shfl_xor(ss, 4, 16);
    ss += __shfl_xor(ss, 8, 16);
    float scl = rsqrtf(ss * (1.f / 64.f) + 1e-6f);
    v0 *= scl; v1 *= scl; v2 *= scl; v3 *= scl;
    v0 += 0.5f * v0 * v0; v1 += 0.5f * v1 * v1; v2 += 0.5f * v2 * v2; v3 += 0.5f * v3 * v3;
  }
  float4 o = {v0, v1, v2, v3};
  *(float4*)(out + (size_t)bt * Csz + c0) = o;
}

// ---------------------------------------------------------------------------
// rms_norm for y -> split-f16 planes (feeds out_mfma)
// ---------------------------------------------------------------------------
__global__ __launch_bounds__(256) void rms_split_kernel(const float* __restrict__ in,
                                                        _Float16* __restrict__ yh,
                                                        _Float16* __restrict__ yl) {
  const int bt = blockIdx.x;
  const int tid = threadIdx.x;
  const int c0 = tid << 2;
  float4 xv = *(const float4*)(in + (size_t)bt * Csz + c0);
  float ss = xv.x * xv.x + xv.y * xv.y + xv.z * xv.z + xv.w * xv.w;
  ss += __shfl_xor(ss, 1, 16);
  ss += __shfl_xor(ss, 2, 16);
  ss += __shfl_xor(ss, 4, 16);
  ss += __shfl_xor(ss, 8, 16);
  float scl = rsqrtf(ss * (1.f / 64.f) + 1e-6f);
  H4u h, l;
  split2(xv.x * scl, xv.y * scl, h.p[0], l.p[0]);
  split2(xv.z * scl, xv.w * scl, h.p[1], l.p[1]);
  *(half4*)(yh + (size_t)bt * Csz + c0) = h.v;
  *(half4*)(yl + (size_t)bt * Csz + c0) = l.v;
}

// ---------------------------------------------------------------------------
// Standalone momentum scan (chunk 0 only). XCD-affinity remapped blockIdx.
// Global scalar loads hoisted before LDS staging (latency hides under it).
// ---------------------------------------------------------------------------
__global__ __launch_bounds__(256) void mom_scan_kernel(const float* __restrict__ Mst,
                                                       const float* __restrict__ kp,
                                                       const float* __restrict__ vp,
                                                       const float* __restrict__ geta,
                                                       const float* __restrict__ gtheta,
                                                       const float* __restrict__ ggamma,
                                                       float* __restrict__ Sst,
                                                       float* __restrict__ chunkS, int ci) {
  __shared__ float Ml[4 * Dsz];
  __shared__ float errl[256];
  __shared__ float kkl[CSz * Dsz];
  __shared__ float gl[CSz], el[CSz], tl[CSz];
  int bh, eb;
  xcd_decode(blockIdx.x, bh, eb);
  const int b = bh >> 4, h = bh & 15;
  const int tid = threadIdx.x;
  const int e = eb * 256 + tid;
  // hoisted global loads (consumed after staging)
  float S = Sst[(size_t)bh * 4096 + e];
  const int tt0 = tid >> 2, vl0 = tid & 3;
  float vv = vp[(((size_t)b * Tsz + ci * CSz + tt0) * Hsz + h) * Dsz + eb * 4 + vl0];
  Ml[tid & 255] = Mst[(size_t)bh * 4096 + eb * 4 * 64 + tid];
#pragma unroll
  for (int i = 0; i < 16; ++i) {
    int idx = i * 256 + tid;
    int t = idx >> 6, k = idx & 63;
    kkl[idx] = kp[(((size_t)b * Tsz + ci * CSz + t) * Hsz + h) * Dsz + k];
  }
  if (tid < CSz) {
    size_t gi = ((size_t)b * Tsz + ci * CSz + tid) * Hsz + h;
    gl[tid] = ggamma[gi];
    el[tid] = geta[gi];
    tl[tid] = gtheta[gi];
  }
  __syncthreads();
  {
    float acc = 0.f;
#pragma unroll
    for (int i = 0; i < 16; ++i) {
      float4 m4 = *(const float4*)&Ml[vl0 * 64 + i * 4];
      float4 k4 = *(const float4*)&kkl[tt0 * 64 + i * 4];
      acc += m4.x * k4.x + m4.y * k4.y + m4.z * k4.z + m4.w * k4.w;
    }
    errl[tt0 * 4 + vl0] = acc - vv;
  }
  __syncthreads();
  const int vloc = tid >> 6;
  const int k = tid & 63;
  float ring[OW];
  float wsum = 0.f;
  float* outp = chunkS + (size_t)bh * CSz * 4096 + e;
#pragma unroll
  for (int t = 0; t < CSz; ++t) {
    float u = 2.f * errl[t * 4 + vloc] * kkl[t * 64 + k];
    float val = gl[t] * u;
    wsum += val;
    if (t >= OW) wsum -= ring[t & (OW - 1)];
    ring[t & (OW - 1)] = val;
    S = tl[t] * S - el[t] * wsum;
    outp[(size_t)t * 4096] = S;
  }
  Sst[(size_t)bh * 4096 + e] = S;
}

// ---------------------------------------------------------------------------
// Fused: memory scan + read (chunk ci), then momentum scan (chunk ci+1).
// ---------------------------------------------------------------------------
__global__ __launch_bounds__(256) void fused_scan_kernel(float* __restrict__ chunkS,
                                                         const float* __restrict__ qp,
                                                         const float* __restrict__ kp,
                                                         const float* __restrict__ vp,
                                                         const float* __restrict__ galpha,
                                                         const float* __restrict__ geta,
                                                         const float* __restrict__ gtheta,
                                                         const float* __restrict__ ggamma,
                                                         float* __restrict__ Mst,
                                                         float* __restrict__ Sst,
                                                         float* __restrict__ ybuf,
                                                         int ci, int do_next) {
  __shared__ float buf[CSz * Dsz];  // ql (mem phase) then kkl (mom phase)
  __shared__ float al[CSz];
  __shared__ float Ml[4 * Dsz];
  __shared__ float errl[256];
  __shared__ float gl[CSz], el[CSz], tl[CSz];
  int bh, eb;
  xcd_decode(blockIdx.x, bh, eb);
  const int b = bh >> 4, h = bh & 15;
  const int tid = threadIdx.x;
  const int w = tid >> 6, lane = tid & 63;
  const int v = eb * 4 + w, k = lane;
  // hoisted: M element load overlaps the staging loop below
  float m = Mst[(size_t)bh * 4096 + v * 64 + k];
  // ---- mem phase (chunk ci) ----
  for (int i = tid; i < CSz * Dsz; i += 256) {
    int t = i >> 6, kk = i & 63;
    buf[i] = qp[(((size_t)b * Tsz + ci * CSz + t) * Hsz + h) * Dsz + kk];
  }
  if (tid < CSz) al[tid] = galpha[((size_t)b * Tsz + ci * CSz + tid) * Hsz + h];
  __syncthreads();
  const float* Xp = chunkS + (size_t)bh * CSz * 4096 + v * 64 + k;
  float* yb = ybuf + (((size_t)b * Tsz + ci * CSz) * Hsz + h) * Dsz + v;
  float x0 = Xp[0], x1 = Xp[4096], x2 = Xp[8192], x3 = Xp[12288];
  for (int t0 = 0; t0 < CSz; t0 += 4) {
    float n0, n1, n2, n3;
    if (t0 + 4 < CSz) {
      const float* Xn = Xp + (size_t)(t0 + 4) * 4096;
      n0 = Xn[0]; n1 = Xn[4096]; n2 = Xn[8192]; n3 = Xn[12288];
    } else {
      n0 = n1 = n2 = n3 = 0.f;
    }
    float m0 = al[t0] * m + x0;
    float m1 = al[t0 + 1] * m0 + x1;
    float m2 = al[t0 + 2] * m1 + x2;
    float m3 = al[t0 + 3] * m2 + x3;
    m = m3;
    float p0 = m0 * buf[(t0 + 0) * 64 + k];
    float p1 = m1 * buf[(t0 + 1) * 64 + k];
    float p2 = m2 * buf[(t0 + 2) * 64 + k];
    float p3 = m3 * buf[(t0 + 3) * 64 + k];
#pragma unroll
    for (int off = 32; off; off >>= 1) {
      p0 += __shfl_xor(p0, off, 64);
      p1 += __shfl_xor(p1, off, 64);
      p2 += __shfl_xor(p2, off, 64);
      p3 += __shfl_xor(p3, off, 64);
    }
    if (lane < 4) {
      float pj = (lane == 0 ? p0 : lane == 1 ? p1 : lane == 2 ? p2 : p3);
      yb[(size_t)(t0 + lane) * Hsz * Dsz] = pj;
    }
    x0 = n0; x1 = n1; x2 = n2; x3 = n3;
  }
  Mst[(size_t)bh * 4096 + v * 64 + k] = m;
  if (!do_next) return;
  // ---- mom phase (chunk ci+1) ----
  const int cj = ci + 1;
  const int e = eb * 256 + tid;
  // hoisted global loads
  float S = Sst[(size_t)bh * 4096 + e];
  const int tt0 = tid >> 2, vl0 = tid & 3;
  float vv = vp[(((size_t)b * Tsz + cj * CSz + tt0) * Hsz + h) * Dsz + eb * 4 + vl0];
  Ml[w * 64 + k] = m;
  __syncthreads();  // ql reads done (buf reusable); Ml visible
#pragma unroll
  for (int i = 0; i < 16; ++i) {
    int idx = i * 256 + tid;
    int t = idx >> 6, kk = idx & 63;
    buf[idx] = kp[(((size_t)b * Tsz + cj * CSz + t) * Hsz + h) * Dsz + kk];
  }
  if (tid < CSz) {
    size_t gi = ((size_t)b * Tsz + cj * CSz + tid) * Hsz + h;
    gl[tid] = ggamma[gi];
    el[tid] = geta[gi];
    tl[tid] = gtheta[gi];
  }
  __syncthreads();
  {
    float acc = 0.f;
#pragma unroll
    for (int i = 0; i < 16; ++i) {
      float4 m4 = *(const float4*)&Ml[vl0 * 64 + i * 4];
      float4 k4 = *(const float4*)&buf[tt0 * 64 + i * 4];
      acc += m4.x * k4.x + m4.y * k4.y + m4.z * k4.z + m4.w * k4.w;
    }
    errl[tt0 * 4 + vl0] = acc - vv;
  }
  __syncthreads();
  const int vloc = tid >> 6;
  float ring[OW];
  float wsum = 0.f;
  float* outp = chunkS + (size_t)bh * CSz * 4096 + e;
#pragma unroll
  for (int t = 0; t < CSz; ++t) {
    float u = 2.f * errl[t * 4 + vloc] * buf[t * 64 + k];
    float val = gl[t] * u;
    wsum += val;
    if (t >= OW) wsum -= ring[t & (OW - 1)];
    ring[t & (OW - 1)] = val;
    S = tl[t] * S - el[t] * wsum;
    outp[(size_t)t * 4096] = S;
  }
  Sst[(size_t)bh * 4096 + e] = S;
}

// ---------------------------------------------------------------------------
// B3: Polar Express via scaled split-f16 MFMA, re-associated dataflow:
//   A = X X^T ; W = A X ; U = A W ; X' = a X + b W + c U
// Stage-2's B-operand (X^T in PT) is stable from B_a until the stage-3
// epilogue -> its 8 fragment reads are issued during stage 1 (overlapping
// the stage-1 split/STS epilogue) and consumed from registers in stage 2.
// ---------------------------------------------------------------------------
__global__ __launch_bounds__(256, 3) void pe_mfma_kernel(float* __restrict__ chunkS) {
  __shared__ __attribute__((aligned(16))) _Float16 PL[6 * 4096];
  __shared__ float red[4];
  const int tid = threadIdx.x;
  const int lane = tid & 63;
  const int wv = tid >> 6;
  int bh, tmat;
  xcd_decode(blockIdx.x, bh, tmat);
  float* G = chunkS + ((size_t)bh * CSz + tmat) * 4096;
  constexpr int PLO = 8192;   // hi->lo plane byte distance
  constexpr int PT = 16384;   // X^T plane pair (fixed role)
  char* const LB = (char*)PL;

  const int mb = (wv >> 1) << 5;
  const int nb = (wv & 1) << 5;
  const int crow = ((lane >> 5) << 2);
  const int ccol = lane & 31;

  int ra_m[4], ra_n[4];
#pragma unroll
  for (int ks = 0; ks < 4; ++ks) {
    int rm = mb + (lane & 31), rn = nb + (lane & 31);
    int cB = (ks << 5) + ((lane >> 5) << 4);
    ra_m[ks] = (rm << 7) + (cB ^ ((rm & 7) << 4));
    ra_n[ks] = (rn << 7) + (cB ^ ((rn & 7) << 4));
  }
  int sa[4];
  {
    const int base = (nb + ccol) << 7;
    const int sw = ((nb + ccol) & 7) << 4;
    const int c2 = crow << 1;
#pragma unroll
    for (int g = 0; g < 4; ++g) sa[g] = base + ((((mb + 8 * g) << 1) ^ sw) + c2);
  }
  int rowa[4];
#pragma unroll
  for (int j = 0; j < 4; ++j) {
    int rr = mb + crow + j;
    rowa[j] = (rr << 7) + (((nb + ccol) << 1) ^ ((rr & 7) << 4));
  }

#define LDF(PB, RA, ks) (*(const half8*)(LB + (PB) + (RA)[ks]))

  // transposed store from packed half2 arrays: plane[col][row] = D[row][col]
  auto STS = [&](int PB, const half2v* h2, const half2v* l2) {
#pragma unroll
    for (int g = 0; g < 4; ++g) {
      H4u hu, lu;
      hu.p[0] = h2[2 * g]; hu.p[1] = h2[2 * g + 1];
      lu.p[0] = l2[2 * g]; lu.p[1] = l2[2 * g + 1];
      *(half4*)(LB + PB + sa[g]) = hu.v;
      *(half4*)(LB + PB + PLO + sa[g]) = lu.v;
    }
  };
  // row store: plane[row][col] = D[row][col]
  auto STR = [&](int PB, const half2v* h2, const half2v* l2) {
#pragma unroll
    for (int r = 0; r < 16; ++r) {
      int off = rowa[r & 3] + ((r >> 2) << 10);
      *(_Float16*)(LB + PB + off) = h2[r >> 1][r & 1];
      *(_Float16*)(LB + PB + PLO + off) = l2[r >> 1][r & 1];
    }
  };

  float Xval[16];
  float ss = 0.f;
#pragma unroll
  for (int r = 0; r < 16; ++r) {
    int rr = mb + crow + (r & 3) + ((r >> 2) << 3);
    float xv = G[rr * 64 + nb + ccol];
    Xval[r] = xv;
    ss += xv * xv;
  }
#pragma unroll
  for (int off = 32; off; off >>= 1) ss += __shfl_xor(ss, off, 64);
  if (lane == 0) red[wv] = ss;
  __syncthreads();
  float tot = red[0] + red[1] + red[2] + red[3];
  float scale = 1.f / ((sqrtf(tot) + 1e-7f) * 1.01f);

  {
    half2v hs2[8], ls2[8];
#pragma unroll
    for (int i = 0; i < 8; ++i) {
      Xval[2 * i] *= scale;
      Xval[2 * i + 1] *= scale;
      split2(Xval[2 * i], Xval[2 * i + 1], hs2[i], ls2[i]);
    }
    STR(0, hs2, ls2);
    STS(PT, hs2, ls2);
  }

  auto iter = [&](float ca, float cb, float cc, int PXB, int PAB, bool last) {
    __syncthreads();  // B_a: X rows + X^T visible; prior stage-3 reads drained
    half8 pth[4], ptl[4];  // stage-2 B-op prefetch (X^T; stable until stage-3 epi)
    // ---- stage 1: A = X X^T ----
    {
      f32x16 accH, accL1, accL2;
#pragma unroll
      for (int r = 0; r < 16; ++r) { accH[r] = 0.f; accL1[r] = 0.f; accL2[r] = 0.f; }
      __builtin_amdgcn_s_setprio(1);
#pragma unroll
      for (int ks = 0; ks < 4; ++ks) {
        half8 ah = LDF(PXB, ra_m, ks), al = LDF(PXB + PLO, ra_m, ks);
        half8 bh, bl;
        if (mb != nb) { bh = LDF(PXB, ra_n, ks); bl = LDF(PXB + PLO, ra_n, ks); }
        else { bh = ah; bl = al; }
        MFMA3(accH, accL1, accL2, ah, al, bh, bl);
      }
      __builtin_amdgcn_s_setprio(0);
      // issue PT prefetch: latency hides under the split epilogue below
#pragma unroll
      for (int ks = 0; ks < 4; ++ks) {
        pth[ks] = LDF(PT, ra_n, ks);
        ptl[ks] = LDF(PT + PLO, ra_n, ks);
      }
      half2v hs2[8], ls2[8];
#pragma unroll
      for (int i = 0; i < 8; ++i) {
        float a0 = accH[2 * i] + (accL1[2 * i] + accL2[2 * i]) * INV_S;
        float a1 = accH[2 * i + 1] + (accL1[2 * i + 1] + accL2[2 * i + 1]) * INV_S;
        split2(a0, a1, hs2[i], ls2[i]);
      }
      STS(PAB, hs2, ls2);
    }
    __syncthreads();  // B_b: A ready; stage-1 X reads drained -> PX reusable
    // ---- stage 2: W = A X (A-op rows of A; B-op X^T from prefetched regs) ----
    half8 fah[4], fal[4];
    f32x16 acWH, acWL1, acWL2;
#pragma unroll
    for (int r = 0; r < 16; ++r) { acWH[r] = 0.f; acWL1[r] = 0.f; acWL2[r] = 0.f; }
    __builtin_amdgcn_s_setprio(1);
#pragma unroll
    for (int ks = 0; ks < 4; ++ks) {
      fah[ks] = LDF(PAB, ra_m, ks);
      fal[ks] = LDF(PAB + PLO, ra_m, ks);
      MFMA3(acWH, acWL1, acWL2, fah[ks], fal[ks], pth[ks], ptl[ks]);
    }
    __builtin_amdgcn_s_setprio(0);
    float Wval[16];
    {
      half2v hs2[8], ls2[8];
#pragma unroll
      for (int i = 0; i < 8; ++i) {
        Wval[2 * i] = acWH[2 * i] + (acWL1[2 * i] + acWL2[2 * i]) * INV_S;
        Wval[2 * i + 1] = acWH[2 * i + 1] + (acWL1[2 * i + 1] + acWL2[2 * i + 1]) * INV_S;
        split2(Wval[2 * i], Wval[2 * i + 1], hs2[i], ls2[i]);
      }
      STS(PXB, hs2, ls2);  // W^T into dead X plane
    }
    __syncthreads();  // B_c: W^T ready; stage-2 PA reads drained
    // ---- stage 3: U = A W (A-op from regs; B-op rows of W^T) ----
    f32x16 acUH, acUL1, acUL2;
#pragma unroll
    for (int r = 0; r < 16; ++r) { acUH[r] = 0.f; acUL1[r] = 0.f; acUL2[r] = 0.f; }
    __builtin_amdgcn_s_setprio(1);
#pragma unroll
    for (int ks = 0; ks < 4; ++ks) {
      half8 bh = LDF(PXB, ra_n, ks), bl = LDF(PXB + PLO, ra_n, ks);
      MFMA3(acUH, acUL1, acUL2, fah[ks], fal[ks], bh, bl);
    }
    __builtin_amdgcn_s_setprio(0);
    if (!last) {
      half2v hs2[8], ls2[8];
#pragma unroll
      for (int i = 0; i < 8; ++i) {
        float u0 = acUH[2 * i] + (acUL1[2 * i] + acUL2[2 * i]) * INV_S;
        float u1 = acUH[2 * i + 1] + (acUL1[2 * i + 1] + acUL2[2 * i + 1]) * INV_S;
        float x0 = ca * Xval[2 * i] + cb * Wval[2 * i] + cc * u0;
        float x1 = ca * Xval[2 * i + 1] + cb * Wval[2 * i + 1] + cc * u1;
        Xval[2 * i] = x0;
        Xval[2 * i + 1] = x1;
        split2(x0, x1, hs2[i], ls2[i]);
      }
      STR(PAB, hs2, ls2);  // X' rows -> dead A plane (next iter's PX)
      STS(PT, hs2, ls2);   // X'^T   -> PT
    } else {
#pragma unroll
      for (int r = 0; r < 16; ++r) {
        int rr = mb + crow + (r & 3) + ((r >> 2) << 3);
        float u = acUH[r] + (acUL1[r] + acUL2[r]) * INV_S;
        G[rr * 64 + nb + ccol] = ca * Xval[r] + cb * Wval[r] + cc * u;
      }
    }
  };

  iter(8.28721201814563f, -23.595886519098837f, 17.300387312530933f, 0, 32768, false);
  iter(4.107059111542203f, -2.9478499167379106f, 0.5448431082926601f, 32768, 0, false);
  iter(3.9486908534822946f, -2.908902115962949f, 0.5518191394370137f, 0, 32768, false);
  iter(3.3184196573706015f, -2.488488024314874f, 0.51004894012372f, 32768, 0, false);
  iter(2.300652019954817f, -1.6689039845747493f, 0.4188073119525673f, 0, 32768, true);
}

// ---------------------------------------------------------------------------
extern "C" void kernel_launch(void* const* d_in, const int* in_sizes, int n_in,
                              void* d_out, int out_size, void* d_ws, size_t ws_size,
                              hipStream_t stream) {
  (void)in_sizes; (void)n_in; (void)out_size; (void)ws_size;
  const float* x   = (const float*)d_in[0];
  const float* Wq  = (const float*)d_in[1];
  const float* Wk  = (const float*)d_in[2];
  const float* Wv  = (const float*)d_in[3];
  const float* Wo  = (const float*)d_in[4];
  const float* cqw = (const float*)d_in[5];
  const float* cqb = (const float*)d_in[6];
  const float* ckw = (const float*)d_in[7];
  const float* ckb = (const float*)d_in[8];
  const float* cvw = (const float*)d_in[9];
  const float* cvb = (const float*)d_in[10];
  const float* Wa  = (const float*)d_in[11];
  const float* We  = (const float*)d_in[12];
  const float* Wt  = (const float*)d_in[13];
  const float* Wg  = (const float*)d_in[14];
  float* out = (float*)d_out;

  float* p = (float*)d_ws;
  const size_t NBTC = (size_t)Bsz * Tsz * Csz;   // 1M
  const size_t NBTH = (size_t)Bsz * Tsz * Hsz;
  const size_t NMAT = (size_t)Bsz * Hsz * Dsz * Dsz;
  const size_t NWW = (size_t)Csz * Csz;          // 1M
  float* qlin = p; p += NBTC;
  float* klin = p; p += NBTC;
  float* vlin = p; p += NBTC;
  float* qp   = p; p += NBTC;
  float* kp   = p; p += NBTC;
  float* vp   = p; p += NBTC;
  float* ga   = p; p += NBTH;
  float* ge   = p; p += NBTH;
  float* gt   = p; p += NBTH;
  float* gg   = p; p += NBTH;
  float* Mst  = p; p += NMAT;
  float* Sst  = p; p += NMAT;
  float* chS  = p; p += (size_t)Bsz * Hsz * CSz * Dsz * Dsz;
  float* ybuf = p; p += NBTC;
  // f16 split planes
  _Float16* hp = (_Float16*)p;
  _Float16* xh  = hp; hp += NBTC;
  _Float16* xl  = hp; hp += NBTC;
  _Float16* Wqh = hp; hp += NWW;
  _Float16* Wql = hp; hp += NWW;
  _Float16* Wkh = hp; hp += NWW;
  _Float16* Wkl = hp; hp += NWW;
  _Float16* Wvh = hp; hp += NWW;
  _Float16* Wvl = hp; hp += NWW;
  _Float16* Woh = hp; hp += NWW;
  _Float16* Wol = hp; hp += NWW;
  _Float16* gWh = hp; hp += (size_t)64 * Csz;
  _Float16* gWl = hp; hp += (size_t)64 * Csz;
  _Float16* yh  = hp; hp += NBTC;
  _Float16* yl  = hp; hp += NBTC;

  hipMemsetAsync(Mst, 0, NMAT * sizeof(float), stream);
  hipMemsetAsync(Sst, 0, NMAT * sizeof(float), stream);

  split_all_kernel<<<dim3(1024, 6), 256, 0, stream>>>(
      x, Wq, Wk, Wv, Wo, Wa, We, Wt, Wg,
      xh, xl, Wqh, Wql, Wkh, Wkl, Wvh, Wvl, Woh, Wol, gWh, gWl);
  qkvg_mfma<<<dim3(16, 49), 256, 0, stream>>>(
      xh, xl, Wqh, Wql, Wkh, Wkl, Wvh, Wvl, gWh, gWl,
      qlin, klin, vlin, ga, ge, gt, gg);
  conv3_kernel<<<dim3(Bsz * Tsz, 3), 256, 0, stream>>>(qlin, klin, vlin, cqw, ckw, cvw,
                                                       cqb, ckb, cvb, qp, kp, vp);

  mom_scan_kernel<<<Bsz * Hsz * 16, 256, 0, stream>>>(Mst, kp, vp, ge, gt, gg, Sst, chS, 0);
  for (int ci = 0; ci < NCHUNK; ++ci) {
    pe_mfma_kernel<<<Bsz * Hsz * CSz, 256, 0, stream>>>(chS);
    fused_scan_kernel<<<Bsz * Hsz * 16, 256, 0, stream>>>(chS, qp, kp, vp, ga, ge, gt, gg,
                                                          Mst, Sst, ybuf, ci,
                                                          ci < NCHUNK - 1 ? 1 : 0);
  }

  rms_split_kernel<<<Bsz * Tsz, 256, 0, stream>>>(ybuf, yh, yl);
  out_mfma<<<dim3(16, 16), 256, 0, stream>>>(yh, yl, Woh, Wol, out);
}

// Round 9
// 823.491 us; speedup vs baseline: 1.0558x; 1.0558x over previous
//
#include <hip/hip_runtime.h>

// Problem constants
constexpr int Bsz = 2, Tsz = 512, Csz = 1024, Hsz = 16, Dsz = 64, CSz = 64;
constexpr int NCHUNK = 8, OW = 8;

typedef __attribute__((ext_vector_type(8))) _Float16 half8;
typedef __attribute__((ext_vector_type(4))) _Float16 half4;
typedef __attribute__((ext_vector_type(2))) _Float16 half2v;
typedef __attribute__((ext_vector_type(2))) __fp16 fp16x2;
typedef __attribute__((ext_vector_type(16))) float f32x16;

constexpr float INV_S = 1.0f / 2048.0f;

union H4u { half4 v; half2v p[2]; };

// fp32 v ~= hi + lo/2048 (f16 pair). Proven precision-adequate by pe kernel.
__device__ __forceinline__ void split_f16(float v, _Float16& hi, _Float16& lo) {
  _Float16 h = (_Float16)v;
  float r = v - (float)h;
  hi = h;
  lo = (_Float16)(r * 2048.0f);
}

// Packed 2-value split via v_cvt_pkrtz_f16_f32. RTZ on hi is pair-safe:
// residual is captured exactly in lo.
__device__ __forceinline__ void split2(float a, float b, half2v& h, half2v& l) {
  fp16x2 hh = __builtin_amdgcn_cvt_pkrtz(a, b);
  half2v hv = __builtin_bit_cast(half2v, hh);
  float ra = (a - (float)hv[0]) * 2048.0f;
  float rb = (b - (float)hv[1]) * 2048.0f;
  h = hv;
  l = __builtin_bit_cast(half2v, __builtin_amdgcn_cvt_pkrtz(ra, rb));
}

// 3-MFMA split product with accL chain split in two.
#define MFMA3(accH, accL1, accL2, ah, al, bh, bl)                             \
  accH = __builtin_amdgcn_mfma_f32_32x32x16_f16(ah, bh, accH, 0, 0, 0);       \
  accL1 = __builtin_amdgcn_mfma_f32_32x32x16_f16(ah, bl, accL1, 0, 0, 0);     \
  accL2 = __builtin_amdgcn_mfma_f32_32x32x16_f16(al, bh, accL2, 0, 0, 0);

// XCD-affinity decode: launched bid -> (bh, idx) with XCD(bid)=bid%8 == bh%8.
__device__ __forceinline__ void xcd_decode(int bid, int& bh, int& idx) {
  bh = (((bid >> 3) & 3) << 3) + (bid & 7);
  idx = bid >> 5;
}

// ---------------------------------------------------------------------------
// One-time fp32 -> (hi,lo) f16 plane conversion.
// ---------------------------------------------------------------------------
__global__ __launch_bounds__(256) void split_all_kernel(
    const float* __restrict__ x, const float* __restrict__ Wq,
    const float* __restrict__ Wk, const float* __restrict__ Wv,
    const float* __restrict__ Wo, const float* __restrict__ Wa,
    const float* __restrict__ We, const float* __restrict__ Wt,
    const float* __restrict__ Wg,
    _Float16* __restrict__ xh, _Float16* __restrict__ xl,
    _Float16* __restrict__ Wqh, _Float16* __restrict__ Wql,
    _Float16* __restrict__ Wkh, _Float16* __restrict__ Wkl,
    _Float16* __restrict__ Wvh, _Float16* __restrict__ Wvl,
    _Float16* __restrict__ Woh, _Float16* __restrict__ Wol,
    _Float16* __restrict__ gWh, _Float16* __restrict__ gWl) {
  const int y = blockIdx.y;
  const int tid = threadIdx.x;
  if (y < 5) {
    const float* src = (y == 0 ? x : y == 1 ? Wq : y == 2 ? Wk : y == 3 ? Wv : Wo);
    _Float16* dh = (y == 0 ? xh : y == 1 ? Wqh : y == 2 ? Wkh : y == 3 ? Wvh : Woh);
    _Float16* dl = (y == 0 ? xl : y == 1 ? Wql : y == 2 ? Wkl : y == 3 ? Wvl : Wol);
    size_t i = ((size_t)blockIdx.x * 256 + tid) * 4;
    float4 v = *(const float4*)(src + i);
    H4u h, l;
    split2(v.x, v.y, h.p[0], l.p[0]);
    split2(v.z, v.w, h.p[1], l.p[1]);
    *(half4*)(dh + i) = h.v;
    *(half4*)(dl + i) = l.v;
  } else {
    if (blockIdx.x >= 64) return;
    size_t i = ((size_t)blockIdx.x * 256 + tid) * 4;
    int gsel = (int)(i >> 14);
    int off = (int)(i & 16383);
    const float* src = (gsel == 0 ? Wa : gsel == 1 ? We : gsel == 2 ? Wt : Wg);
    float4 v = *(const float4*)(src + off);
    H4u h, l;
    split2(v.x, v.y, h.p[0], l.p[0]);
    split2(v.z, v.w, h.p[1], l.p[1]);
    *(half4*)(gWh + i) = h.v;
    *(half4*)(gWl + i) = l.v;
  }
}

// ---------------------------------------------------------------------------
// Split-f16 MFMA GEMM core: 64x64 output tile, K=1024, O = A @ B^T.
// Software-pipelined: next K-tile's global loads issue after the store
// barrier and overlap the MFMA cluster (T14).
// ---------------------------------------------------------------------------
__device__ __forceinline__ void gemm64_core(const _Float16* __restrict__ Agh,
                                            const _Float16* __restrict__ Agl,
                                            const _Float16* __restrict__ Bgh,
                                            const _Float16* __restrict__ Bgl,
                                            int m0, int n0, int tid, char* LB,
                                            f32x16& accH, f32x16& accL1, f32x16& accL2) {
  const int lane = tid & 63, wv = tid >> 6;
  const int mb = (wv >> 1) << 5, nb = (wv & 1) << 5;
  const int lr = tid >> 2;             // staging row 0..63
  const int lch = (tid & 3) << 4;      // half col {0,16,32,48}
  const int cb = lch << 1;             // byte col
  const int wb0 = (lr << 7) + (cb ^ ((lr & 7) << 4));
  const int wb1 = (lr << 7) + ((cb + 16) ^ ((lr & 7) << 4));
  const _Float16* pah = Agh + (size_t)(m0 + lr) * Csz + lch;
  const _Float16* pal = Agl + (size_t)(m0 + lr) * Csz + lch;
  const _Float16* pbh = Bgh + (size_t)(n0 + lr) * Csz + lch;
  const _Float16* pbl = Bgl + (size_t)(n0 + lr) * Csz + lch;
  int ra_m[4], ra_n[4];
#pragma unroll
  for (int ks = 0; ks < 4; ++ks) {
    int rm = mb + (lane & 31), rn = nb + (lane & 31);
    int cB = (ks << 5) + ((lane >> 5) << 4);
    ra_m[ks] = (rm << 7) + (cB ^ ((rm & 7) << 4));
    ra_n[ks] = (rn << 7) + (cB ^ ((rn & 7) << 4));
  }
#pragma unroll
  for (int r = 0; r < 16; ++r) { accH[r] = 0.f; accL1[r] = 0.f; accL2[r] = 0.f; }
  // prologue loads (k0 = 0)
  half8 vah0 = *(const half8*)(pah), vah1 = *(const half8*)(pah + 8);
  half8 val0 = *(const half8*)(pal), val1 = *(const half8*)(pal + 8);
  half8 vbh0 = *(const half8*)(pbh), vbh1 = *(const half8*)(pbh + 8);
  half8 vbl0 = *(const half8*)(pbl), vbl1 = *(const half8*)(pbl + 8);
  for (int k0 = 0; k0 < Csz; k0 += 64) {
    __syncthreads();  // prior MFMA reads of LB done
    *(half8*)(LB + wb0) = vah0;          *(half8*)(LB + wb1) = vah1;
    *(half8*)(LB + 8192 + wb0) = val0;   *(half8*)(LB + 8192 + wb1) = val1;
    *(half8*)(LB + 16384 + wb0) = vbh0;  *(half8*)(LB + 16384 + wb1) = vbh1;
    *(half8*)(LB + 24576 + wb0) = vbl0;  *(half8*)(LB + 24576 + wb1) = vbl1;
    __syncthreads();  // LB ready
    if (k0 + 64 < Csz) {  // next-tile loads overlap the MFMAs below
      vah0 = *(const half8*)(pah + k0 + 64); vah1 = *(const half8*)(pah + k0 + 72);
      val0 = *(const half8*)(pal + k0 + 64); val1 = *(const half8*)(pal + k0 + 72);
      vbh0 = *(const half8*)(pbh + k0 + 64); vbh1 = *(const half8*)(pbh + k0 + 72);
      vbl0 = *(const half8*)(pbl + k0 + 64); vbl1 = *(const half8*)(pbl + k0 + 72);
    }
    __builtin_amdgcn_s_setprio(1);
#pragma unroll
    for (int ks = 0; ks < 4; ++ks) {
      half8 ah = *(const half8*)(LB + ra_m[ks]);
      half8 al = *(const half8*)(LB + 8192 + ra_m[ks]);
      half8 bh = *(const half8*)(LB + 16384 + ra_n[ks]);
      half8 bl = *(const half8*)(LB + 24576 + ra_n[ks]);
      MFMA3(accH, accL1, accL2, ah, al, bh, bl);
    }
    __builtin_amdgcn_s_setprio(0);
  }
}

// ---------------------------------------------------------------------------
// Fused QKV + gates GEMM via split-f16 MFMA. Grid (16, 49).
// ---------------------------------------------------------------------------
__global__ __launch_bounds__(256) void qkvg_mfma(
    const _Float16* __restrict__ xh, const _Float16* __restrict__ xl,
    const _Float16* __restrict__ Wqh, const _Float16* __restrict__ Wql,
    const _Float16* __restrict__ Wkh, const _Float16* __restrict__ Wkl,
    const _Float16* __restrict__ Wvh, const _Float16* __restrict__ Wvl,
    const _Float16* __restrict__ gWh, const _Float16* __restrict__ gWl,
    float* __restrict__ qlin, float* __restrict__ klin, float* __restrict__ vlin,
    float* __restrict__ ga, float* __restrict__ ge,
    float* __restrict__ gt, float* __restrict__ gg) {
  __shared__ __attribute__((aligned(16))) char LB[32768];
  const int tid = threadIdx.x;
  const int by = blockIdx.y;
  const int m0 = blockIdx.x << 6;
  const _Float16 *Bh, *Bl;
  int n0;
  if (by < 48) {
    const int mat = by >> 4;
    n0 = (by & 15) << 6;
    Bh = (mat == 0 ? Wqh : mat == 1 ? Wkh : Wvh);
    Bl = (mat == 0 ? Wql : mat == 1 ? Wkl : Wvl);
  } else {
    n0 = 0;
    Bh = gWh;
    Bl = gWl;
  }
  f32x16 accH, accL1, accL2;
  gemm64_core(xh, xl, Bh, Bl, m0, n0, tid, LB, accH, accL1, accL2);
  const int lane = tid & 63, wv = tid >> 6;
  const int mb = (wv >> 1) << 5, nb = (wv & 1) << 5;
  const int crow = (lane >> 5) << 2, ccol = lane & 31;
  if (by < 48) {
    const int mat = by >> 4;
    float* O = (mat == 0 ? qlin : mat == 1 ? klin : vlin);
#pragma unroll
    for (int r = 0; r < 16; ++r) {
      int row = mb + crow + (r & 3) + ((r >> 2) << 3);
      O[(size_t)(m0 + row) * Csz + n0 + nb + ccol] = accH[r] + (accL1[r] + accL2[r]) * INV_S;
    }
  } else {
    const int col = nb + ccol;
    const int gsel = col >> 4, h = col & 15;
    float* outp = (gsel == 0 ? ga : gsel == 1 ? ge : gsel == 2 ? gt : gg);
#pragma unroll
    for (int r = 0; r < 16; ++r) {
      int row = mb + crow + (r & 3) + ((r >> 2) << 3);
      float v = accH[r] + (accL1[r] + accL2[r]) * INV_S;
      outp[(size_t)(m0 + row) * Hsz + h] = 1.f / (1.f + expf(-v));
    }
  }
}

// ---------------------------------------------------------------------------
// Out-projection GEMM via split-f16 MFMA. Grid (16,16).
// ---------------------------------------------------------------------------
__global__ __launch_bounds__(256) void out_mfma(
    const _Float16* __restrict__ yh, const _Float16* __restrict__ yl,
    const _Float16* __restrict__ Woh, const _Float16* __restrict__ Wol,
    float* __restrict__ out) {
  __shared__ __attribute__((aligned(16))) char LB[32768];
  const int tid = threadIdx.x;
  const int m0 = blockIdx.x << 6, n0 = blockIdx.y << 6;
  f32x16 accH, accL1, accL2;
  gemm64_core(yh, yl, Woh, Wol, m0, n0, tid, LB, accH, accL1, accL2);
  const int lane = tid & 63, wv = tid >> 6;
  const int mb = (wv >> 1) << 5, nb = (wv & 1) << 5;
  const int crow = (lane >> 5) << 2, ccol = lane & 31;
#pragma unroll
  for (int r = 0; r < 16; ++r) {
    int row = mb + crow + (r & 3) + ((r >> 2) << 3);
    out[(size_t)(m0 + row) * Csz + n0 + nb + ccol] = accH[r] + (accL1[r] + accL2[r]) * INV_S;
  }
}

// ---------------------------------------------------------------------------
// Causal depthwise conv (K=4) + optional rms_norm/poly. Grid (B*T, 3).
// ---------------------------------------------------------------------------
__global__ __launch_bounds__(256) void conv3_kernel(const float* __restrict__ qlin,
                                                    const float* __restrict__ klin,
                                                    const float* __restrict__ vlin,
                                                    const float* __restrict__ cqw,
                                                    const float* __restrict__ ckw,
                                                    const float* __restrict__ cvw,
                                                    const float* __restrict__ cqb,
                                                    const float* __restrict__ ckb,
                                                    const float* __restrict__ cvb,
                                                    float* __restrict__ qp,
                                                    float* __restrict__ kp,
                                                    float* __restrict__ vp) {
  const int sel = blockIdx.y;
  const float* lin = (sel == 0 ? qlin : sel == 1 ? klin : vlin);
  const float* w = (sel == 0 ? cqw : sel == 1 ? ckw : cvw);
  const float* bias = (sel == 0 ? cqb : sel == 1 ? ckb : cvb);
  float* out = (sel == 0 ? qp : sel == 1 ? kp : vp);
  const int do_norm = (sel < 2);
  const int bt = blockIdx.x;
  const int b = bt >> 9, t = bt & 511;
  const int tid = threadIdx.x;
  const int c0 = tid << 2;
  float4 bv = *(const float4*)&bias[c0];
  float v0 = bv.x, v1 = bv.y, v2 = bv.z, v3 = bv.w;
  float4 w0 = *(const float4*)&w[(c0 + 0) * 4];
  float4 w1 = *(const float4*)&w[(c0 + 1) * 4];
  float4 w2 = *(const float4*)&w[(c0 + 2) * 4];
  float4 w3 = *(const float4*)&w[(c0 + 3) * 4];
  const float* base = lin + (size_t)b * Tsz * Csz + c0;
#pragma unroll
  for (int j = 0; j < 4; ++j) {
    int tt = t - 3 + j;
    if (tt < 0) continue;
    float4 xv = *(const float4*)(base + (size_t)tt * Csz);
    v0 += xv.x * (&w0.x)[j];
    v1 += xv.y * (&w1.x)[j];
    v2 += xv.z * (&w2.x)[j];
    v3 += xv.w * (&w3.x)[j];
  }
  if (do_norm) {
    float ss = v0 * v0 + v1 * v1 + v2 * v2 + v3 * v3;
    ss += __shfl_xor(ss, 1, 16);
    ss += __shfl_xor(ss, 2, 16);
    ss += __shfl_xor(ss, 4, 16);
    ss += __shfl_xor(ss, 8, 16);
    float scl = rsqrtf(ss * (1.f / 64.f) + 1e-6f);
    v0 *= scl; v1 *= scl; v2 *= scl; v3 *= scl;
    v0 += 0.5f * v0 * v0; v1 += 0.5f * v1 * v1; v2 += 0.5f * v2 * v2; v3 += 0.5f * v3 * v3;
  }
  float4 o = {v0, v1, v2, v3};
  *(float4*)(out + (size_t)bt * Csz + c0) = o;
}

// ---------------------------------------------------------------------------
// rms_norm for y -> split-f16 planes (feeds out_mfma)
// ---------------------------------------------------------------------------
__global__ __launch_bounds__(256) void rms_split_kernel(const float* __restrict__ in,
                                                        _Float16* __restrict__ yh,
                                                        _Float16* __restrict__ yl) {
  const int bt = blockIdx.x;
  const int tid = threadIdx.x;
  const int c0 = tid << 2;
  float4 xv = *(const float4*)(in + (size_t)bt * Csz + c0);
  float ss = xv.x * xv.x + xv.y * xv.y + xv.z * xv.z + xv.w * xv.w;
  ss += __shfl_xor(ss, 1, 16);
  ss += __shfl_xor(ss, 2, 16);
  ss += __shfl_xor(ss, 4, 16);
  ss += __shfl_xor(ss, 8, 16);
  float scl = rsqrtf(ss * (1.f / 64.f) + 1e-6f);
  H4u h, l;
  split2(xv.x * scl, xv.y * scl, h.p[0], l.p[0]);
  split2(xv.z * scl, xv.w * scl, h.p[1], l.p[1]);
  *(half4*)(yh + (size_t)bt * Csz + c0) = h.v;
  *(half4*)(yl + (size_t)bt * Csz + c0) = l.v;
}

// ---------------------------------------------------------------------------
// Standalone momentum scan (chunk 0 only). XCD-affinity remapped blockIdx.
// ---------------------------------------------------------------------------
__global__ __launch_bounds__(256) void mom_scan_kernel(const float* __restrict__ Mst,
                                                       const float* __restrict__ kp,
                                                       const float* __restrict__ vp,
                                                       const float* __restrict__ geta,
                                                       const float* __restrict__ gtheta,
                                                       const float* __restrict__ ggamma,
                                                       float* __restrict__ Sst,
                                                       float* __restrict__ chunkS, int ci) {
  __shared__ float Ml[4 * Dsz];
  __shared__ float errl[256];
  __shared__ float kkl[CSz * Dsz];
  __shared__ float gl[CSz], el[CSz], tl[CSz];
  int bh, eb;
  xcd_decode(blockIdx.x, bh, eb);
  const int b = bh >> 4, h = bh & 15;
  const int tid = threadIdx.x;
  const int e = eb * 256 + tid;
  // hoisted global loads (consumed after staging)
  float S = Sst[(size_t)bh * 4096 + e];
  const int tt0 = tid >> 2, vl0 = tid & 3;
  float vv = vp[(((size_t)b * Tsz + ci * CSz + tt0) * Hsz + h) * Dsz + eb * 4 + vl0];
  Ml[tid & 255] = Mst[(size_t)bh * 4096 + eb * 4 * 64 + tid];
#pragma unroll
  for (int i = 0; i < 16; ++i) {
    int idx = i * 256 + tid;
    int t = idx >> 6, k = idx & 63;
    kkl[idx] = kp[(((size_t)b * Tsz + ci * CSz + t) * Hsz + h) * Dsz + k];
  }
  if (tid < CSz) {
    size_t gi = ((size_t)b * Tsz + ci * CSz + tid) * Hsz + h;
    gl[tid] = ggamma[gi];
    el[tid] = geta[gi];
    tl[tid] = gtheta[gi];
  }
  __syncthreads();
  {
    float acc = 0.f;
#pragma unroll
    for (int i = 0; i < 16; ++i) {
      float4 m4 = *(const float4*)&Ml[vl0 * 64 + i * 4];
      float4 k4 = *(const float4*)&kkl[tt0 * 64 + i * 4];
      acc += m4.x * k4.x + m4.y * k4.y + m4.z * k4.z + m4.w * k4.w;
    }
    errl[tt0 * 4 + vl0] = acc - vv;
  }
  __syncthreads();
  const int vloc = tid >> 6;
  const int k = tid & 63;
  float ring[OW];
  float wsum = 0.f;
  float* outp = chunkS + (size_t)bh * CSz * 4096 + e;
#pragma unroll
  for (int t = 0; t < CSz; ++t) {
    float u = 2.f * errl[t * 4 + vloc] * kkl[t * 64 + k];
    float val = gl[t] * u;
    wsum += val;
    if (t >= OW) wsum -= ring[t & (OW - 1)];
    ring[t & (OW - 1)] = val;
    S = tl[t] * S - el[t] * wsum;
    outp[(size_t)t * 4096] = S;
  }
  Sst[(size_t)bh * 4096 + e] = S;
}

// ---------------------------------------------------------------------------
// Fused: memory scan + read (chunk ci), then momentum scan (chunk ci+1).
// mem phase: ALL 64 Xo loads issued up front (statically indexed, full
// unroll) -> latency-flat against L2; kernel is grid-limited (2 blocks/CU)
// so the +64 VGPR cost no occupancy.
// ---------------------------------------------------------------------------
__global__ __launch_bounds__(256) void fused_scan_kernel(float* __restrict__ chunkS,
                                                         const float* __restrict__ qp,
                                                         const float* __restrict__ kp,
                                                         const float* __restrict__ vp,
                                                         const float* __restrict__ galpha,
                                                         const float* __restrict__ geta,
                                                         const float* __restrict__ gtheta,
                                                         const float* __restrict__ ggamma,
                                                         float* __restrict__ Mst,
                                                         float* __restrict__ Sst,
                                                         float* __restrict__ ybuf,
                                                         int ci, int do_next) {
  __shared__ float buf[CSz * Dsz];  // ql (mem phase) then kkl (mom phase)
  __shared__ float al[CSz];
  __shared__ float Ml[4 * Dsz];
  __shared__ float errl[256];
  __shared__ float gl[CSz], el[CSz], tl[CSz];
  int bh, eb;
  xcd_decode(blockIdx.x, bh, eb);
  const int b = bh >> 4, h = bh & 15;
  const int tid = threadIdx.x;
  const int w = tid >> 6, lane = tid & 63;
  const int v = eb * 4 + w, k = lane;
  // hoisted: M element load overlaps the staging loop below
  float m = Mst[(size_t)bh * 4096 + v * 64 + k];
  // ---- mem phase (chunk ci) ----
  for (int i = tid; i < CSz * Dsz; i += 256) {
    int t = i >> 6, kk = i & 63;
    buf[i] = qp[(((size_t)b * Tsz + ci * CSz + t) * Hsz + h) * Dsz + kk];
  }
  if (tid < CSz) al[tid] = galpha[((size_t)b * Tsz + ci * CSz + tid) * Hsz + h];
  __syncthreads();
  const float* Xp = chunkS + (size_t)bh * CSz * 4096 + v * 64 + k;
  float* yb = ybuf + (((size_t)b * Tsz + ci * CSz) * Hsz + h) * Dsz + v;
  float xv[CSz];
#pragma unroll
  for (int t = 0; t < CSz; ++t) xv[t] = Xp[(size_t)t * 4096];
#pragma unroll
  for (int t0 = 0; t0 < CSz; t0 += 4) {
    float m0 = al[t0] * m + xv[t0];
    float m1 = al[t0 + 1] * m0 + xv[t0 + 1];
    float m2 = al[t0 + 2] * m1 + xv[t0 + 2];
    float m3 = al[t0 + 3] * m2 + xv[t0 + 3];
    m = m3;
    float p0 = m0 * buf[(t0 + 0) * 64 + k];
    float p1 = m1 * buf[(t0 + 1) * 64 + k];
    float p2 = m2 * buf[(t0 + 2) * 64 + k];
    float p3 = m3 * buf[(t0 + 3) * 64 + k];
#pragma unroll
    for (int off = 32; off; off >>= 1) {
      p0 += __shfl_xor(p0, off, 64);
      p1 += __shfl_xor(p1, off, 64);
      p2 += __shfl_xor(p2, off, 64);
      p3 += __shfl_xor(p3, off, 64);
    }
    if (lane < 4) {
      float pj = (lane == 0 ? p0 : lane == 1 ? p1 : lane == 2 ? p2 : p3);
      yb[(size_t)(t0 + lane) * Hsz * Dsz] = pj;
    }
  }
  Mst[(size_t)bh * 4096 + v * 64 + k] = m;
  if (!do_next) return;
  // ---- mom phase (chunk ci+1) ----
  const int cj = ci + 1;
  const int e = eb * 256 + tid;
  // hoisted global loads
  float S = Sst[(size_t)bh * 4096 + e];
  const int tt0 = tid >> 2, vl0 = tid & 3;
  float vv = vp[(((size_t)b * Tsz + cj * CSz + tt0) * Hsz + h) * Dsz + eb * 4 + vl0];
  Ml[w * 64 + k] = m;
  __syncthreads();  // ql reads done (buf reusable); Ml visible
#pragma unroll
  for (int i = 0; i < 16; ++i) {
    int idx = i * 256 + tid;
    int t = idx >> 6, kk = idx & 63;
    buf[idx] = kp[(((size_t)b * Tsz + cj * CSz + t) * Hsz + h) * Dsz + kk];
  }
  if (tid < CSz) {
    size_t gi = ((size_t)b * Tsz + cj * CSz + tid) * Hsz + h;
    gl[tid] = ggamma[gi];
    el[tid] = geta[gi];
    tl[tid] = gtheta[gi];
  }
  __syncthreads();
  {
    float acc = 0.f;
#pragma unroll
    for (int i = 0; i < 16; ++i) {
      float4 m4 = *(const float4*)&Ml[vl0 * 64 + i * 4];
      float4 k4 = *(const float4*)&buf[tt0 * 64 + i * 4];
      acc += m4.x * k4.x + m4.y * k4.y + m4.z * k4.z + m4.w * k4.w;
    }
    errl[tt0 * 4 + vl0] = acc - vv;
  }
  __syncthreads();
  const int vloc = tid >> 6;
  float ring[OW];
  float wsum = 0.f;
  float* outp = chunkS + (size_t)bh * CSz * 4096 + e;
#pragma unroll
  for (int t = 0; t < CSz; ++t) {
    float u = 2.f * errl[t * 4 + vloc] * buf[t * 64 + k];
    float val = gl[t] * u;
    wsum += val;
    if (t >= OW) wsum -= ring[t & (OW - 1)];
    ring[t & (OW - 1)] = val;
    S = tl[t] * S - el[t] * wsum;
    outp[(size_t)t * 4096] = S;
  }
  Sst[(size_t)bh * 4096 + e] = S;
}

// ---------------------------------------------------------------------------
// B3: Polar Express via scaled split-f16 MFMA, re-associated dataflow:
//   A = X X^T ; W = A X ; U = A W ; X' = a X + b W + c U
// Stage-2's B-operand (X^T) prefetched during stage 1. Stage-3 accumulator
// pre-initialized with (ca X + cb W)/cc so the MFMA chain accumulates the
// full polynomial (epilogue = cc*accH + cc*INV_S*(L1+L2)).
// ---------------------------------------------------------------------------
__global__ __launch_bounds__(256, 3) void pe_mfma_kernel(float* __restrict__ chunkS) {
  __shared__ __attribute__((aligned(16))) _Float16 PL[6 * 4096];
  __shared__ float red[4];
  const int tid = threadIdx.x;
  const int lane = tid & 63;
  const int wv = tid >> 6;
  int bh, tmat;
  xcd_decode(blockIdx.x, bh, tmat);
  float* G = chunkS + ((size_t)bh * CSz + tmat) * 4096;
  constexpr int PLO = 8192;   // hi->lo plane byte distance
  constexpr int PT = 16384;   // X^T plane pair (fixed role)
  char* const LB = (char*)PL;

  const int mb = (wv >> 1) << 5;
  const int nb = (wv & 1) << 5;
  const int crow = ((lane >> 5) << 2);
  const int ccol = lane & 31;

  int ra_m[4], ra_n[4];
#pragma unroll
  for (int ks = 0; ks < 4; ++ks) {
    int rm = mb + (lane & 31), rn = nb + (lane & 31);
    int cB = (ks << 5) + ((lane >> 5) << 4);
    ra_m[ks] = (rm << 7) + (cB ^ ((rm & 7) << 4));
    ra_n[ks] = (rn << 7) + (cB ^ ((rn & 7) << 4));
  }
  int sa[4];
  {
    const int base = (nb + ccol) << 7;
    const int sw = ((nb + ccol) & 7) << 4;
    const int c2 = crow << 1;
#pragma unroll
    for (int g = 0; g < 4; ++g) sa[g] = base + ((((mb + 8 * g) << 1) ^ sw) + c2);
  }
  int rowa[4];
#pragma unroll
  for (int j = 0; j < 4; ++j) {
    int rr = mb + crow + j;
    rowa[j] = (rr << 7) + (((nb + ccol) << 1) ^ ((rr & 7) << 4));
  }

#define LDF(PB, RA, ks) (*(const half8*)(LB + (PB) + (RA)[ks]))

  // transposed store from packed half2 arrays: plane[col][row] = D[row][col]
  auto STS = [&](int PB, const half2v* h2, const half2v* l2) {
#pragma unroll
    for (int g = 0; g < 4; ++g) {
      H4u hu, lu;
      hu.p[0] = h2[2 * g]; hu.p[1] = h2[2 * g + 1];
      lu.p[0] = l2[2 * g]; lu.p[1] = l2[2 * g + 1];
      *(half4*)(LB + PB + sa[g]) = hu.v;
      *(half4*)(LB + PB + PLO + sa[g]) = lu.v;
    }
  };
  // row store: plane[row][col] = D[row][col]
  auto STR = [&](int PB, const half2v* h2, const half2v* l2) {
#pragma unroll
    for (int r = 0; r < 16; ++r) {
      int off = rowa[r & 3] + ((r >> 2) << 10);
      *(_Float16*)(LB + PB + off) = h2[r >> 1][r & 1];
      *(_Float16*)(LB + PB + PLO + off) = l2[r >> 1][r & 1];
    }
  };

  float Xval[16];
  float ss = 0.f;
#pragma unroll
  for (int r = 0; r < 16; ++r) {
    int rr = mb + crow + (r & 3) + ((r >> 2) << 3);
    float xv = G[rr * 64 + nb + ccol];
    Xval[r] = xv;
    ss += xv * xv;
  }
#pragma unroll
  for (int off = 32; off; off >>= 1) ss += __shfl_xor(ss, off, 64);
  if (lane == 0) red[wv] = ss;
  __syncthreads();
  float tot = red[0] + red[1] + red[2] + red[3];
  float scale = 1.f / ((sqrtf(tot) + 1e-7f) * 1.01f);

  {
    half2v hs2[8], ls2[8];
#pragma unroll
    for (int i = 0; i < 8; ++i) {
      Xval[2 * i] *= scale;
      Xval[2 * i + 1] *= scale;
      split2(Xval[2 * i], Xval[2 * i + 1], hs2[i], ls2[i]);
    }
    STR(0, hs2, ls2);
    STS(PT, hs2, ls2);
  }

  auto iter = [&](float ca, float cb, float cc, int PXB, int PAB, bool last) {
    const float rca = ca / cc, rcb = cb / cc, ccS = cc * INV_S;
    __syncthreads();  // B_a: X rows + X^T visible; prior stage-3 reads drained
    half8 pth[4], ptl[4];  // stage-2 B-op prefetch (X^T; stable until stage-3 epi)
    // ---- stage 1: A = X X^T ----
    {
      f32x16 accH, accL1, accL2;
#pragma unroll
      for (int r = 0; r < 16; ++r) { accH[r] = 0.f; accL1[r] = 0.f; accL2[r] = 0.f; }
      __builtin_amdgcn_s_setprio(1);
#pragma unroll
      for (int ks = 0; ks < 4; ++ks) {
        half8 ah = LDF(PXB, ra_m, ks), al = LDF(PXB + PLO, ra_m, ks);
        half8 bh, bl;
        if (mb != nb) { bh = LDF(PXB, ra_n, ks); bl = LDF(PXB + PLO, ra_n, ks); }
        else { bh = ah; bl = al; }
        MFMA3(accH, accL1, accL2, ah, al, bh, bl);
      }
      __builtin_amdgcn_s_setprio(0);
      // issue PT prefetch: latency hides under the split epilogue below
#pragma unroll
      for (int ks = 0; ks < 4; ++ks) {
        pth[ks] = LDF(PT, ra_n, ks);
        ptl[ks] = LDF(PT + PLO, ra_n, ks);
      }
      half2v hs2[8], ls2[8];
#pragma unroll
      for (int i = 0; i < 8; ++i) {
        float a0 = accH[2 * i] + (accL1[2 * i] + accL2[2 * i]) * INV_S;
        float a1 = accH[2 * i + 1] + (accL1[2 * i + 1] + accL2[2 * i + 1]) * INV_S;
        split2(a0, a1, hs2[i], ls2[i]);
      }
      STS(PAB, hs2, ls2);
    }
    __syncthreads();  // B_b: A ready; stage-1 X reads drained -> PX reusable
    // ---- stage 2: W = A X (A-op rows of A; B-op X^T from prefetched regs) ----
    half8 fah[4], fal[4];
    f32x16 acWH, acWL1, acWL2;
#pragma unroll
    for (int r = 0; r < 16; ++r) { acWH[r] = 0.f; acWL1[r] = 0.f; acWL2[r] = 0.f; }
    __builtin_amdgcn_s_setprio(1);
#pragma unroll
    for (int ks = 0; ks < 4; ++ks) {
      fah[ks] = LDF(PAB, ra_m, ks);
      fal[ks] = LDF(PAB + PLO, ra_m, ks);
      MFMA3(acWH, acWL1, acWL2, fah[ks], fal[ks], pth[ks], ptl[ks]);
    }
    __builtin_amdgcn_s_setprio(0);
    float Wval[16];
    {
      half2v hs2[8], ls2[8];
#pragma unroll
      for (int i = 0; i < 8; ++i) {
        Wval[2 * i] = acWH[2 * i] + (acWL1[2 * i] + acWL2[2 * i]) * INV_S;
        Wval[2 * i + 1] = acWH[2 * i + 1] + (acWL1[2 * i + 1] + acWL2[2 * i + 1]) * INV_S;
        split2(Wval[2 * i], Wval[2 * i + 1], hs2[i], ls2[i]);
      }
      STS(PXB, hs2, ls2);  // W^T into dead X plane
    }
    __syncthreads();  // B_c: W^T ready; stage-2 PA reads drained
    // ---- stage 3: U = A W with polynomial pre-init in accH ----
    f32x16 acUH, acUL1, acUL2;
#pragma unroll
    for (int r = 0; r < 16; ++r) {
      acUH[r] = rca * Xval[r] + rcb * Wval[r];
      acUL1[r] = 0.f; acUL2[r] = 0.f;
    }
    __builtin_amdgcn_s_setprio(1);
#pragma unroll
    for (int ks = 0; ks < 4; ++ks) {
      half8 bh = LDF(PXB, ra_n, ks), bl = LDF(PXB + PLO, ra_n, ks);
      MFMA3(acUH, acUL1, acUL2, fah[ks], fal[ks], bh, bl);
    }
    __builtin_amdgcn_s_setprio(0);
    if (!last) {
      half2v hs2[8], ls2[8];
#pragma unroll
      for (int i = 0; i < 8; ++i) {
        float x0 = cc * acUH[2 * i] + ccS * (acUL1[2 * i] + acUL2[2 * i]);
        float x1 = cc * acUH[2 * i + 1] + ccS * (acUL1[2 * i + 1] + acUL2[2 * i + 1]);
        Xval[2 * i] = x0;
        Xval[2 * i + 1] = x1;
        split2(x0, x1, hs2[i], ls2[i]);
      }
      STR(PAB, hs2, ls2);  // X' rows -> dead A plane (next iter's PX)
      STS(PT, hs2, ls2);   // X'^T   -> PT
    } else {
#pragma unroll
      for (int r = 0; r < 16; ++r) {
        int rr = mb + crow + (r & 3) + ((r >> 2) << 3);
        G[rr * 64 + nb + ccol] = cc * acUH[r] + ccS * (acUL1[r] + acUL2[r]);
      }
    }
  };

  iter(8.28721201814563f, -23.595886519098837f, 17.300387312530933f, 0, 32768, false);
  iter(4.107059111542203f, -2.9478499167379106f, 0.5448431082926601f, 32768, 0, false);
  iter(3.9486908534822946f, -2.908902115962949f, 0.5518191394370137f, 0, 32768, false);
  iter(3.3184196573706015f, -2.488488024314874f, 0.51004894012372f, 32768, 0, false);
  iter(2.300652019954817f, -1.6689039845747493f, 0.4188073119525673f, 0, 32768, true);
}

// ---------------------------------------------------------------------------
extern "C" void kernel_launch(void* const* d_in, const int* in_sizes, int n_in,
                              void* d_out, int out_size, void* d_ws, size_t ws_size,
                              hipStream_t stream) {
  (void)in_sizes; (void)n_in; (void)out_size; (void)ws_size;
  const float* x   = (const float*)d_in[0];
  const float* Wq  = (const float*)d_in[1];
  const float* Wk  = (const float*)d_in[2];
  const float* Wv  = (const float*)d_in[3];
  const float* Wo  = (const float*)d_in[4];
  const float* cqw = (const float*)d_in[5];
  const float* cqb = (const float*)d_in[6];
  const float* ckw = (const float*)d_in[7];
  const float* ckb = (const float*)d_in[8];
  const float* cvw = (const float*)d_in[9];
  const float* cvb = (const float*)d_in[10];
  const float* Wa  = (const float*)d_in[11];
  const float* We  = (const float*)d_in[12];
  const float* Wt  = (const float*)d_in[13];
  const float* Wg  = (const float*)d_in[14];
  float* out = (float*)d_out;

  float* p = (float*)d_ws;
  const size_t NBTC = (size_t)Bsz * Tsz * Csz;   // 1M
  const size_t NBTH = (size_t)Bsz * Tsz * Hsz;
  const size_t NMAT = (size_t)Bsz * Hsz * Dsz * Dsz;
  const size_t NWW = (size_t)Csz * Csz;          // 1M
  float* qlin = p; p += NBTC;
  float* klin = p; p += NBTC;
  float* vlin = p; p += NBTC;
  float* qp   = p; p += NBTC;
  float* kp   = p; p += NBTC;
  float* vp   = p; p += NBTC;
  float* ga   = p; p += NBTH;
  float* ge   = p; p += NBTH;
  float* gt   = p; p += NBTH;
  float* gg   = p; p += NBTH;
  float* Mst  = p; p += NMAT;
  float* Sst  = p; p += NMAT;
  float* chS  = p; p += (size_t)Bsz * Hsz * CSz * Dsz * Dsz;
  float* ybuf = p; p += NBTC;
  // f16 split planes
  _Float16* hp = (_Float16*)p;
  _Float16* xh  = hp; hp += NBTC;
  _Float16* xl  = hp; hp += NBTC;
  _Float16* Wqh = hp; hp += NWW;
  _Float16* Wql = hp; hp += NWW;
  _Float16* Wkh = hp; hp += NWW;
  _Float16* Wkl = hp; hp += NWW;
  _Float16* Wvh = hp; hp += NWW;
  _Float16* Wvl = hp; hp += NWW;
  _Float16* Woh = hp; hp += NWW;
  _Float16* Wol = hp; hp += NWW;
  _Float16* gWh = hp; hp += (size_t)64 * Csz;
  _Float16* gWl = hp; hp += (size_t)64 * Csz;
  _Float16* yh  = hp; hp += NBTC;
  _Float16* yl  = hp; hp += NBTC;

  hipMemsetAsync(Mst, 0, NMAT * sizeof(float), stream);
  hipMemsetAsync(Sst, 0, NMAT * sizeof(float), stream);

  split_all_kernel<<<dim3(1024, 6), 256, 0, stream>>>(
      x, Wq, Wk, Wv, Wo, Wa, We, Wt, Wg,
      xh, xl, Wqh, Wql, Wkh, Wkl, Wvh, Wvl, Woh, Wol, gWh, gWl);
  qkvg_mfma<<<dim3(16, 49), 256, 0, stream>>>(
      xh, xl, Wqh, Wql, Wkh, Wkl, Wvh, Wvl, gWh, gWl,
      qlin, klin, vlin, ga, ge, gt, gg);
  conv3_kernel<<<dim3(Bsz * Tsz, 3), 256, 0, stream>>>(qlin, klin, vlin, cqw, ckw, cvw,
                                                       cqb, ckb, cvb, qp, kp, vp);

  mom_scan_kernel<<<Bsz * Hsz * 16, 256, 0, stream>>>(Mst, kp, vp, ge, gt, gg, Sst, chS, 0);
  for (int ci = 0; ci < NCHUNK; ++ci) {
    pe_mfma_kernel<<<Bsz * Hsz * CSz, 256, 0, stream>>>(chS);
    fused_scan_kernel<<<Bsz * Hsz * 16, 256, 0, stream>>>(chS, qp, kp, vp, ga, ge, gt, gg,
                                                          Mst, Sst, ybuf, ci,
                                                          ci < NCHUNK - 1 ? 1 : 0);
  }

  rms_split_kernel<<<Bsz * Tsz, 256, 0, stream>>>(ybuf, yh, yl);
  out_mfma<<<dim3(16, 16), 256, 0, stream>>>(yh, yl, Woh, Wol, out);
}